// Round 6
// baseline (1075.646 us; speedup 1.0000x reference)
//
#include <hip/hip_runtime.h>

#define TLEN 512
#define HID  64

typedef _Float16 half8  __attribute__((ext_vector_type(8)));
typedef float    f32x4  __attribute__((ext_vector_type(4)));
typedef float    f32x16 __attribute__((ext_vector_type(16)));

__device__ __forceinline__ float rcp_fast(float x) { return __builtin_amdgcn_rcpf(x); }
__device__ __forceinline__ float exp2_fast(float x) {
#if __has_builtin(__builtin_amdgcn_exp2f)
    return __builtin_amdgcn_exp2f(x);
#else
    float r; asm("v_exp_f32 %0, %1" : "=v"(r) : "v"(x)); return r;
#endif
}

// R17: 2 independent blocks/CU (R12's proven anti-lockstep, dead ~60 cyc)
// + 32x32x16 MFMA (8.5 cyc/instr vs 17: same gate-GEMM at half the MFMA
// issue for the same dup). 512 blocks x 256 thr; block = 4 real rows,
// B = 32 cols = 4 real x 8 dup; wave = 16 units as 2 tiles of 32 rows
// (gate-major row = 8g+ul), K-chain 4. Census: 1 act/lane (invariant).
// Gate extraction: D row = (reg&3)+8*(reg>>2)+4*(lane>>5) => lane (col n,
// half s) act-unit u = 16w+8t+4s+d2 (t=(n>>2)&1, d2=n>>3), gate g at
// acc_t[4g+d2]: 7-cndmask select per gate (constant reg indices only).
// Pre-gates merged post-select (C_in = 0). Cell = R15 merged-ratio
// (5 exp2 + 2 rcp, exp2-domain scales folded into A/wih/bias). No setprio,
// no x-pipeline (R16 showed both regress).
__global__ __launch_bounds__(256) __attribute__((amdgpu_waves_per_eu(2, 2)))
void lstm_c32(const float* __restrict__ x,
              const float* __restrict__ W_ih,
              const float* __restrict__ W_hh,
              const float* __restrict__ b_ih,
              const float* __restrict__ b_hh,
              const float* __restrict__ W_d,
              const float* __restrict__ b_d,
              float* __restrict__ out) {
    __shared__ __align__(16) float    xs[4][516];     // 4 x rows
    __shared__ __align__(16) _Float16 hbuf[2][4][80]; // ping-pong h, pad 80

    const int tid = threadIdx.x;
    const int L   = tid & 63;
    const int w   = tid >> 6;        // wave 0..3, owns units [16w, 16w+16)
    const int r0  = blockIdx.x * 4;

    // ---- stage x rows (float4) ----
    for (int i = tid; i < 4 * 128; i += 256) {
        const int r = i >> 7, t4 = (i & 127) * 4;
        *(float4*)&xs[r][t4] = *(const float4*)&x[(size_t)(r0 + r) * TLEN + t4];
    }
    // ---- zero both h buffers (h0 = 0) ----
    for (int i = tid; i < 2 * 4 * 80; i += 256)
        ((_Float16*)hbuf)[i] = (_Float16)0.0f;

    const float K  = 1.44269504f;    // log2 e
    const float K2 = 2.0f * K;

    // ---- resident A-frags af[t][q]: 32x32x16, A[m][k], m=L&31,
    //      k = 16q + 8*(L>>5) + i. Tile t rows are gate-major: m = 8g+ul,
    //      unit u = 16w + 8t + ul. Gate scale folded in (-K i,f,o; +2K g).
    half8 af[2][4];
    {
        const int m  = L & 31;
        const int g  = m >> 3;
        const int ul = m & 7;
        const int sa = L >> 5;
        const float sg = (g == 2) ? K2 : -K;
#pragma unroll
        for (int t = 0; t < 2; ++t) {
            const int u = 16 * w + 8 * t + ul;
            const float* row = &W_hh[(size_t)(g * HID + u) * HID];
#pragma unroll
            for (int q = 0; q < 4; ++q) {
                const float* p = row + 16 * q + 8 * sa;
                half8 hf;
#pragma unroll
                for (int i = 0; i < 8; ++i) hf[i] = (_Float16)(sg * p[i]);
                af[t][q] = hf;
            }
        }
    }

    // ---- lane role: col n = L&31 (b = n&3 real row, 8-way dup), half s ----
    const int n  = L & 31;
    const int s  = L >> 5;
    const int b  = n & 3;
    const int tt = (n >> 2) & 1;     // tile select
    const int d2 = n >> 3;           // reg select (0..3)
    const int u  = 16 * w + 8 * tt + 4 * s + d2;  // lane's act unit
    const bool e1 = (d2 & 1) != 0;
    const bool e2 = (d2 & 2) != 0;
    const bool tb = tt != 0;
    // 64 lanes <-> 64 distinct (b,u) per wave: exactly one act per lane.

    // pre-gate params, pre-scaled into exp2 domain
    float wih[4], bias[4];
#pragma unroll
    for (int g = 0; g < 4; ++g) {
        const float sg = (g == 2) ? K2 : -K;
        wih[g]  = sg * W_ih[g * HID + u];
        bias[g] = sg * (b_ih[g * HID + u] + b_hh[g * HID + u]);
    }

    const float* xrow = &xs[b][0];
    // B-frag base: k = 16q + 8s + i -> element [b][8s + 16q], b128 each
    const _Float16* h0r = &hbuf[0][b][8 * s];
    const _Float16* h1r = &hbuf[1][b][8 * s];
    _Float16*       h0w = &hbuf[0][0][0];
    _Float16*       h1w = &hbuf[1][0][0];
    const int widx = b * 80 + u;
    const f32x16 z16 = {0,0,0,0, 0,0,0,0, 0,0,0,0, 0,0,0,0};
    float S = 0.0f;                  // state: S = 2K * c

    __syncthreads();

    auto step = [&](const _Float16* rd, _Float16* wr, float xt) {
        // pre-gates (merged after select)
        const float pre0 = fmaf(xt, wih[0], bias[0]);
        const float pre1 = fmaf(xt, wih[1], bias[1]);
        const float pre2 = fmaf(xt, wih[2], bias[2]);
        const float pre3 = fmaf(xt, wih[3], bias[3]);

        const half8 b0 = *(const half8*)(rd);
        const half8 b1 = *(const half8*)(rd + 16);
        const half8 b2 = *(const half8*)(rd + 32);
        const half8 b3 = *(const half8*)(rd + 48);

        // two independent K-chains of depth 4 (one per tile)
        f32x16 a0 = __builtin_amdgcn_mfma_f32_32x32x16_f16(af[0][0], b0, z16, 0, 0, 0);
        f32x16 a1 = __builtin_amdgcn_mfma_f32_32x32x16_f16(af[1][0], b0, z16, 0, 0, 0);
        a0 = __builtin_amdgcn_mfma_f32_32x32x16_f16(af[0][1], b1, a0, 0, 0, 0);
        a1 = __builtin_amdgcn_mfma_f32_32x32x16_f16(af[1][1], b1, a1, 0, 0, 0);
        a0 = __builtin_amdgcn_mfma_f32_32x32x16_f16(af[0][2], b2, a0, 0, 0, 0);
        a1 = __builtin_amdgcn_mfma_f32_32x32x16_f16(af[1][2], b2, a1, 0, 0, 0);
        a0 = __builtin_amdgcn_mfma_f32_32x32x16_f16(af[0][3], b3, a0, 0, 0, 0);
        a1 = __builtin_amdgcn_mfma_f32_32x32x16_f16(af[1][3], b3, a1, 0, 0, 0);

        // gate g of unit u lives at acc_tt[4g + d2]: 7-op select per gate
        float dv[4];
#pragma unroll
        for (int g = 0; g < 4; ++g) {
            const float x0 = e1 ? a0[4 * g + 1] : a0[4 * g + 0];
            const float x1 = e1 ? a0[4 * g + 3] : a0[4 * g + 2];
            const float vA = e2 ? x1 : x0;
            const float y0 = e1 ? a1[4 * g + 1] : a1[4 * g + 0];
            const float y1 = e1 ? a1[4 * g + 3] : a1[4 * g + 2];
            const float vB = e2 ? y1 : y0;
            dv[g] = tb ? vB : vA;
        }

        // args already scaled: -K*a (i,f,o), +2K*a (g)
        const float ei = exp2_fast(dv[0] + pre0);
        const float ef = exp2_fast(dv[1] + pre1);
        const float eg = exp2_fast(dv[2] + pre2);
        const float eo = exp2_fast(dv[3] + pre3);

        // merged-ratio cell on S = 2K*c: 2 rcp total
        const float A1  = 1.0f + ei;
        const float B1  = 1.0f + eg;
        const float E1  = 1.0f + ef;
        const float C1K = fmaf(eg, K2, -K2);     // 2K*(eg-1)
        const float Pig = A1 * B1;               // (1+ei)(1+eg)
        const float Dde = E1 * Pig;              // common denominator
        const float CEK = C1K * E1;
        const float num = fmaf(S, Pig, CEK);
        S = num * rcp_fast(Dde);                 // S' = 2K*(gf*c + gi*gg)
        const float ec = exp2_fast(S);
        const float F1 = 1.0f + eo;
        const float G1 = 1.0f + ec;
        const float H1 = ec - 1.0f;
        const float hv = H1 * rcp_fast(F1 * G1); // go * tanh(c')
        wr[widx] = (_Float16)hv;  // one write per lane, 64 unique (b,u)
    };

    for (int t = 0; t < TLEN; t += 4) {
        // x register-blocking: one b128 read covers 4 steps (16B-aligned)
        const float4 xq = *(const float4*)&xrow[t];
        step(h0r, h1w, xq.x);
        __syncthreads();
        step(h1r, h0w, xq.y);
        __syncthreads();
        step(h0r, h1w, xq.z);
        __syncthreads();
        step(h1r, h0w, xq.w);
        __syncthreads();
    }

    // ---- epilogue: wave w reduces batch row w (final h in hbuf[0]) ----
    float pv = (float)hbuf[0][w][L] * W_d[L];
#pragma unroll
    for (int off = 32; off > 0; off >>= 1)
        pv += __shfl_xor(pv, off, 64);
    if (L == 0)
        out[r0 + w] = pv + b_d[0];
}

extern "C" void kernel_launch(void* const* d_in, const int* in_sizes, int n_in,
                              void* d_out, int out_size, void* d_ws, size_t ws_size,
                              hipStream_t stream) {
    const float* x    = (const float*)d_in[0];
    const float* W_ih = (const float*)d_in[1];
    const float* W_hh = (const float*)d_in[2];
    const float* b_ih = (const float*)d_in[3];
    const float* b_hh = (const float*)d_in[4];
    const float* W_d  = (const float*)d_in[5];
    const float* b_d  = (const float*)d_in[6];
    float* out = (float*)d_out;

    dim3 grid(512);    // 2048 / 4 rows per block -> 2 independent blocks/CU
    dim3 block(256);   // 4 waves; each SIMD hosts waves of 2 different blocks
    lstm_c32<<<grid, block, 0, stream>>>(x, W_ih, W_hh, b_ih, b_hh, W_d, b_d, out);
}

// Round 7
// 206.459 us; speedup vs baseline: 5.2100x; 5.2100x over previous
//
#include <hip/hip_runtime.h>

#define TLEN 512
#define HID  64

typedef _Float16 half8 __attribute__((ext_vector_type(8)));
typedef float    f32x4 __attribute__((ext_vector_type(4)));

__device__ __forceinline__ float rcp_fast(float x) { return __builtin_amdgcn_rcpf(x); }
__device__ __forceinline__ float exp2_fast(float x) {
#if __has_builtin(__builtin_amdgcn_exp2f)
    return __builtin_amdgcn_exp2f(x);
#else
    float r; asm("v_exp_f32 %0, %1" : "=v"(r) : "v"(x)); return r;
#endif
}

// R18 = R12 shape (2 independent blocks/CU: proven 93% SIMD-busy, dead ~60
// cyc vs R15's ~260) + R14/R15 cell (merged-ratio 5exp2+2rcp, scales folded
// into A/wih/bias: proven -71 VALU cyc/wave). R17 post-mortem fixed the MFMA
// model: 32x32 is 32 cyc/SIMD-issue (no win); 16x16x32 @ 17 cyc stands.
// Shape: 512 blocks x 256 thr (4 waves); block owns 4 real rows (16 cols =
// 4 real x 4 dup); wave owns 16 units as 4 A-tiles, depth-2 K-chains
// (select once from 4 results: 12 cndmask; chain latency hidden by the
// sibling block's stagger). Census: exactly 1 act/lane. No setprio, no
// x-pipeline (R16: both regress).
__global__ __launch_bounds__(256) __attribute__((amdgpu_waves_per_eu(2, 2)))
void lstm_r18(const float* __restrict__ x,
              const float* __restrict__ W_ih,
              const float* __restrict__ W_hh,
              const float* __restrict__ b_ih,
              const float* __restrict__ b_hh,
              const float* __restrict__ W_d,
              const float* __restrict__ b_d,
              float* __restrict__ out) {
    __shared__ __align__(16) float    xs[4][516];     // 4 x rows
    __shared__ __align__(16) _Float16 hbuf[2][4][80]; // ping-pong h, pad 80

    const int tid = threadIdx.x;
    const int L   = tid & 63;
    const int w   = tid >> 6;        // wave 0..3, owns units [16w, 16w+16)
    const int r0  = blockIdx.x * 4;

    // ---- stage x rows (float4) ----
    for (int i = tid; i < 4 * 128; i += 256) {
        const int r = i >> 7, t4 = (i & 127) * 4;
        *(float4*)&xs[r][t4] = *(const float4*)&x[(size_t)(r0 + r) * TLEN + t4];
    }
    // ---- zero both h buffers (h0 = 0) ----
    for (int i = tid; i < 2 * 4 * 80; i += 256)
        ((_Float16*)hbuf)[i] = (_Float16)0.0f;

    const float K  = 1.44269504f;    // log2 e
    const float K2 = 2.0f * K;

    // ---- resident A-frags: A[m][k], m=L&15, k=32q+(L>>4)*8+i ----
    // tile tt -> unit 16w+4tt+(m>>2), gate m&3 (i,f,g,o)
    // Gate scale folded into A: s = -K (i,f,o), +2K (g).
    half8 af[4][2];
    {
        const int m  = L & 15;
        const int g  = m & 3;
        const int kb = (L >> 4) * 8;
        const float sg = (g == 2) ? K2 : -K;
#pragma unroll
        for (int tt = 0; tt < 4; ++tt) {
            const int uu = 16 * w + 4 * tt + (m >> 2);
            const float* row = &W_hh[(size_t)(g * HID + uu) * HID];
#pragma unroll
            for (int q = 0; q < 2; ++q) {
                const float* p = row + 32 * q + kb;
                half8 hf;
#pragma unroll
                for (int i = 0; i < 8; ++i) hf[i] = (_Float16)(sg * p[i]);
                af[tt][q] = hf;
            }
        }
    }

    // ---- lane role: col c, batch b (4 real rows), 2-bit dup selects tile ----
    const int c   = L & 15;
    const int b   = c & 3;
    const int dup = c >> 2;                  // 0..3
    const int u   = 16 * w + 4 * dup + (L >> 4);
    const bool d1 = dup & 1;
    const bool d2 = dup & 2;
    // 64 lanes <-> 64 distinct (b,u): exactly one activation per lane.

    // pre-gate params, pre-scaled into exp2 domain (same s as A rows)
    float wih[4], bias[4];
#pragma unroll
    for (int g = 0; g < 4; ++g) {
        const float s = (g == 2) ? K2 : -K;
        wih[g]  = s * W_ih[g * HID + u];
        bias[g] = s * (b_ih[g * HID + u] + b_hh[g * HID + u]);
    }

    const float* xrow = &xs[b][0];
    const int koff = (L >> 4) * 8;
    const _Float16* h0r = &hbuf[0][b][0];
    _Float16*       h0w = &hbuf[0][0][0];
    const _Float16* h1r = &hbuf[1][b][0];
    _Float16*       h1w = &hbuf[1][0][0];
    const int widx = b * 80 + u;     // write offset within a buffer
    const f32x4 zero = {0.0f, 0.0f, 0.0f, 0.0f};
    float S = 0.0f;                  // state: S = 2K * c

    __syncthreads();

    auto step = [&](const _Float16* hin, _Float16* hout, float xt) {
        // pre-gates: ready before MFMA results are consumed
        const float pre0 = fmaf(xt, wih[0], bias[0]);
        const float pre1 = fmaf(xt, wih[1], bias[1]);
        const float pre2 = fmaf(xt, wih[2], bias[2]);
        const float pre3 = fmaf(xt, wih[3], bias[3]);

        half8 b0 = *(const half8*)(hin + koff);
        half8 b1 = *(const half8*)(hin + koff + 32);

        // 4 independent depth-2 K-chains (latency hidden by sibling block)
        f32x4 t0 = __builtin_amdgcn_mfma_f32_16x16x32_f16(af[0][0], b0, zero, 0, 0, 0);
        f32x4 t1 = __builtin_amdgcn_mfma_f32_16x16x32_f16(af[1][0], b0, zero, 0, 0, 0);
        f32x4 t2 = __builtin_amdgcn_mfma_f32_16x16x32_f16(af[2][0], b0, zero, 0, 0, 0);
        f32x4 t3 = __builtin_amdgcn_mfma_f32_16x16x32_f16(af[3][0], b0, zero, 0, 0, 0);
        t0 = __builtin_amdgcn_mfma_f32_16x16x32_f16(af[0][1], b1, t0, 0, 0, 0);
        t1 = __builtin_amdgcn_mfma_f32_16x16x32_f16(af[1][1], b1, t1, 0, 0, 0);
        t2 = __builtin_amdgcn_mfma_f32_16x16x32_f16(af[2][1], b1, t2, 0, 0, 0);
        t3 = __builtin_amdgcn_mfma_f32_16x16x32_f16(af[3][1], b1, t3, 0, 0, 0);

        // single 2-bit tile select (12 cndmask)
        f32x4 dS;
#pragma unroll
        for (int r = 0; r < 4; ++r) {
            const float a01 = d1 ? t1[r] : t0[r];
            const float a23 = d1 ? t3[r] : t2[r];
            dS[r] = d2 ? a23 : a01;
        }

        // args already scaled: -K*a (i,f,o), +2K*a (g)
        const float ei = exp2_fast(dS[0] + pre0);
        const float ef = exp2_fast(dS[1] + pre1);
        const float eg = exp2_fast(dS[2] + pre2);
        const float eo = exp2_fast(dS[3] + pre3);

        // merged-ratio cell on S = 2K*c: 2 rcp total
        const float A1  = 1.0f + ei;
        const float B1  = 1.0f + eg;
        const float E1  = 1.0f + ef;
        const float C1K = fmaf(eg, K2, -K2);     // 2K*(eg-1)
        const float Pig = A1 * B1;               // (1+ei)(1+eg)
        const float Dde = E1 * Pig;              // common denominator
        const float CEK = C1K * E1;
        const float num = fmaf(S, Pig, CEK);
        S = num * rcp_fast(Dde);                 // S' = 2K*(gf*c + gi*gg)
        const float ec = exp2_fast(S);
        const float F1 = 1.0f + eo;
        const float G1 = 1.0f + ec;
        const float H1 = ec - 1.0f;
        const float hv = H1 * rcp_fast(F1 * G1); // go * tanh(c')
        hout[widx] = (_Float16)hv;  // one write per lane, 64 unique (b,u)
    };

    for (int t = 0; t < TLEN; t += 4) {
        // x register-blocking: one b128 read covers 4 steps (16B-aligned)
        const float4 xq = *(const float4*)&xrow[t];
        step(h0r, h1w, xq.x);
        __syncthreads();
        step(h1r, h0w, xq.y);
        __syncthreads();
        step(h0r, h1w, xq.z);
        __syncthreads();
        step(h1r, h0w, xq.w);
        __syncthreads();
    }

    // ---- epilogue: wave w reduces batch row w (final h in hbuf[0]) ----
    float pv = (float)hbuf[0][w][L] * W_d[L];
#pragma unroll
    for (int off = 32; off > 0; off >>= 1)
        pv += __shfl_xor(pv, off, 64);
    if (L == 0)
        out[r0 + w] = pv + b_d[0];
}

extern "C" void kernel_launch(void* const* d_in, const int* in_sizes, int n_in,
                              void* d_out, int out_size, void* d_ws, size_t ws_size,
                              hipStream_t stream) {
    const float* x    = (const float*)d_in[0];
    const float* W_ih = (const float*)d_in[1];
    const float* W_hh = (const float*)d_in[2];
    const float* b_ih = (const float*)d_in[3];
    const float* b_hh = (const float*)d_in[4];
    const float* W_d  = (const float*)d_in[5];
    const float* b_d  = (const float*)d_in[6];
    float* out = (float*)d_out;

    dim3 grid(512);    // 2048 / 4 rows per block -> 2 independent blocks/CU
    dim3 block(256);   // 4 waves; each SIMD hosts waves of 2 different blocks
    lstm_r18<<<grid, block, 0, stream>>>(x, W_ih, W_hh, b_ih, b_hh, W_d, b_d, out);
}